// Round 1
// baseline (5096.091 us; speedup 1.0000x reference)
//
#include <hip/hip_runtime.h>
#include <hip/hip_bf16.h>
#include <math.h>

#define E_EDGES 320000
#define N_NODES 10000
#define EB 64        // edges per block
#define TB 512       // threads per block

__device__ __forceinline__ float silu_f(float v) {
  return __fdividef(v, 1.f + __expf(-v));
}

__device__ __forceinline__ void atomAddF(float* p, float v) {
  __hip_atomic_fetch_add(p, v, __ATOMIC_RELAXED, __HIP_MEMORY_SCOPE_AGENT);
}

// Generic MLP layer: 64 edges in LDS, 512 threads, 8 output-groups (one per wave).
// in/out are LDS pointers with leading dims LDI/LDO. W is global [KIN][KOUT] row-major.
template<int KIN, int KOUT, bool ACT, int LDI, int LDO>
__device__ __forceinline__ void mlp_layer(const float* __restrict__ W, float scale,
                                          const float* in, float* out) {
  const int t = threadIdx.x;
  const int e = t & 63;
  constexpr int CH = KOUT / 8;
  const int o0 = __builtin_amdgcn_readfirstlane((t >> 6) * CH);
  float acc[CH];
#pragma unroll
  for (int j = 0; j < CH; ++j) acc[j] = 0.f;
  for (int i = 0; i < KIN; ++i) {
    float a = in[e * LDI + i];
    const float* wr = W + i * KOUT + o0;
#pragma unroll
    for (int j = 0; j < CH; ++j) acc[j] = fmaf(a, wr[j], acc[j]);
  }
#pragma unroll
  for (int j = 0; j < CH; ++j) {
    float v = acc[j] * scale;
    if (ACT) v = silu_f(v);
    out[e * LDO + o0 + j] = v;
  }
}

// -------------------- K0: init node accumulators --------------------
__global__ void k0_init(float* __restrict__ nwY0, float* __restrict__ nwY1,
                        float* __restrict__ out, const int* __restrict__ species,
                        const float* __restrict__ pe) {
  int idx = blockIdx.x * blockDim.x + threadIdx.x;
  int stride = gridDim.x * blockDim.x;
  for (int i = idx; i < N_NODES; i += stride) out[i] = pe[species[i]];
  for (int i = idx; i < N_NODES * 128; i += stride) { nwY0[i] = 0.f; nwY1[i] = 0.f; }
}

// -------------------- K1: edge MLP + w0 scatter --------------------
__global__ __launch_bounds__(TB) void k1_edge(
    const float* __restrict__ vectors, const int* __restrict__ senders,
    const int* __restrict__ receivers, const int* __restrict__ species,
    const float* __restrict__ emb, const float* __restrict__ We0,
    const float* __restrict__ We1, const float* __restrict__ We2,
    const float* __restrict__ We3, const float* __restrict__ Wwvec,
    const float* __restrict__ Ww, float* __restrict__ xg,
    float* __restrict__ wvg, float* __restrict__ nwY0) {
  __shared__ float bufA[64 * 257];
  __shared__ float bufB[64 * 257];
  __shared__ float sY[64 * 4];
  __shared__ float sEnv[64];
  __shared__ int sSend[64];
  __shared__ int sSpecS[64];
  __shared__ int sSpecR[64];
  const int t = threadIdx.x;
  const int blk = blockIdx.x;
  const int e = t & 63;

  if (t < 64) {
    int eg = blk * EB + t;
    float vx = vectors[eg * 3 + 0], vy = vectors[eg * 3 + 1], vz = vectors[eg * 3 + 2];
    float d = fmaxf(sqrtf(vx * vx + vy * vy + vz * vz), 1e-6f);
    float d2 = d * d, d3 = d2 * d, d6 = d3 * d3;
    float env = (d < 1.f) ? (1.f + d6 * (-28.f + 48.f * d - 21.f * d2)) : 0.f;
    float inv_d = 1.f / d;
    const float SQ3 = 1.7320508075688772f;
    sY[t * 4 + 0] = 1.f;
    sY[t * 4 + 1] = SQ3 * vx * inv_d;
    sY[t * 4 + 2] = SQ3 * vy * inv_d;
    sY[t * 4 + 3] = SQ3 * vz * inv_d;
    sEnv[t] = env;
    sSend[t] = senders[eg];
    const float SQ2 = 1.4142135623730951f;
    const float PI_F = 3.14159265358979323846f;
    float c = SQ2 * inv_d * env;
#pragma unroll
    for (int n = 1; n <= 8; ++n)
      bufA[t * 257 + (n - 1)] = c * __sinf((float)n * PI_F * d);
  } else if (t < 128) {
    int e2 = t - 64; int eg = blk * EB + e2;
    sSpecS[e2] = species[senders[eg]];
  } else if (t < 192) {
    int e2 = t - 128; int eg = blk * EB + e2;
    sSpecR[e2] = species[receivers[eg]];
  }
  __syncthreads();
  for (int idx = t; idx < 64 * 32; idx += TB) {
    int ee = idx >> 5, j = idx & 31;
    bufA[ee * 257 + 8 + j]  = emb[sSpecS[ee] * 32 + j];
    bufA[ee * 257 + 40 + j] = emb[sSpecR[ee] * 32 + j];
  }
  __syncthreads();
  mlp_layer<72, 64, true, 257, 257>(We0, 0.11785113f, bufA, bufB);
  __syncthreads();
  mlp_layer<64, 128, true, 257, 257>(We1, 0.125f, bufB, bufA);
  __syncthreads();
  mlp_layer<128, 256, true, 257, 257>(We2, 0.08838835f, bufA, bufB);
  __syncthreads();
  mlp_layer<256, 64, false, 257, 257>(We3, 0.0625f, bufB, bufA);
  __syncthreads();
  // x = env * x ; store
  for (int idx = t; idx < 64 * 64; idx += TB) {
    int ee = idx >> 6, j = idx & 63;
    float v = bufA[ee * 257 + j] * sEnv[ee];
    bufA[ee * 257 + j] = v;
    xg[(blk * EB + ee) * 64 + j] = v;
  }
  __syncthreads();
  // wv = x @ Wwvec / 8
  if (t < 64) {
    float acc = 0.f;
    for (int i = 0; i < 64; ++i) acc = fmaf(bufA[t * 257 + i], Wwvec[i], acc);
    acc *= 0.125f;
    wvg[blk * EB + t] = acc;
  }
  // w0 = x @ Ww[0] / 8 ; scatter w0 (x) Y into nwY0[sender]
  {
    const int c0 = __builtin_amdgcn_readfirstlane((t >> 6) * 4);
    float acc[4] = {0.f, 0.f, 0.f, 0.f};
    for (int i = 0; i < 64; ++i) {
      float a = bufA[e * 257 + i];
      const float* wr = Ww + i * 32 + c0;
#pragma unroll
      for (int j = 0; j < 4; ++j) acc[j] = fmaf(a, wr[j], acc[j]);
    }
    int s = sSend[e];
#pragma unroll
    for (int j = 0; j < 4; ++j) {
      float w0 = acc[j] * 0.125f;
#pragma unroll
      for (int k = 0; k < 4; ++k)
        atomAddF(&nwY0[s * 128 + (c0 + j) * 4 + k], w0 * sY[e * 4 + k]);
    }
  }
}

// -------------------- K2: layer l=0 --------------------
__global__ __launch_bounds__(TB) void k2_layer0(
    const float* __restrict__ vectors, const int* __restrict__ senders,
    const float* __restrict__ Wvinit, const float* __restrict__ WV0,
    const float* __restrict__ Wm0, const float* __restrict__ Wm1,
    const float* __restrict__ Wm2, const float* __restrict__ Ww1,
    float* __restrict__ xg, const float* __restrict__ wvg,
    float* __restrict__ h1g, const float* __restrict__ nwY0,
    float* __restrict__ nwY1, const float* __restrict__ vepsp) {
  __shared__ float bufA[64 * 97];
  __shared__ float bufB[64 * 97];
  __shared__ float sNW[64 * 128];
  __shared__ float sY[64 * 4];
  __shared__ float sEnv[64];
  __shared__ int sSend[64];
  __shared__ float sWv[64];
  const int t = threadIdx.x;
  const int blk = blockIdx.x;
  const int e = t & 63;
  const float eps = rsqrtf(1.f + log1pf(__expf(vepsp[0])));
  const float INV66 = 1.f / 66.f;
  const float INV_SQRT3 = 0.57735026918962576f;
  const float INV_SQRT32 = 0.17677669529663689f;

  if (t < 64) {
    int eg = blk * EB + t;
    float vx = vectors[eg * 3 + 0], vy = vectors[eg * 3 + 1], vz = vectors[eg * 3 + 2];
    float d = fmaxf(sqrtf(vx * vx + vy * vy + vz * vz), 1e-6f);
    float d2 = d * d, d3 = d2 * d, d6 = d3 * d3;
    sEnv[t] = (d < 1.f) ? (1.f + d6 * (-28.f + 48.f * d - 21.f * d2)) : 0.f;
    float inv_d = 1.f / d;
    const float SQ3 = 1.7320508075688772f;
    sY[t * 4 + 0] = 1.f;
    sY[t * 4 + 1] = SQ3 * vx * inv_d;
    sY[t * 4 + 2] = SQ3 * vy * inv_d;
    sY[t * 4 + 3] = SQ3 * vz * inv_d;
    sSend[t] = senders[eg];
    sWv[t] = wvg[eg];
  }
  __syncthreads();
  for (int idx = t; idx < 64 * 64; idx += TB) {
    int ee = idx >> 6, j = idx & 63;
    bufA[ee * 97 + j] = xg[(blk * EB + ee) * 64 + j];
  }
  for (int idx = t; idx < 64 * 128; idx += TB) {
    int ee = idx >> 7, j = idx & 127;
    sNW[ee * 128 + j] = nwY0[sSend[ee] * 128 + j];
  }
  __syncthreads();
  const int c0 = __builtin_amdgcn_readfirstlane((t >> 6) * 4);
  // s_out into bufA cols 64..95
  {
#pragma unroll
    for (int j = 0; j < 4; ++j) {
      int c = c0 + j;
      float sk = sNW[e * 128 + c * 4 + 1] * sY[e * 4 + 1]
               + sNW[e * 128 + c * 4 + 2] * sY[e * 4 + 2]
               + sNW[e * 128 + c * 4 + 3] * sY[e * 4 + 3];
      float h0 = sWv[e] * INV66 * Wvinit[c];
      bufA[e * 97 + 64 + c] = h0 * eps * sk * INV_SQRT3;
    }
  }
  // h1[f] = sum_c (eps*nw[c,0])*h0[c]*WV0[c,f] / sqrt(32)
  {
    float acc[4] = {0.f, 0.f, 0.f, 0.f};
    for (int c = 0; c < 32; ++c) {
      float hc = eps * sNW[e * 128 + c * 4] * sWv[e] * INV66 * Wvinit[c];
      const float* wr = WV0 + c * 32 + c0;
#pragma unroll
      for (int j = 0; j < 4; ++j) acc[j] = fmaf(hc, wr[j], acc[j]);
    }
    int eg = blk * EB + e;
#pragma unroll
    for (int j = 0; j < 4; ++j) h1g[eg * 32 + c0 + j] = acc[j] * INV_SQRT32;
  }
  __syncthreads();
  mlp_layer<96, 64, true, 97, 97>(Wm0, 0.10206207f, bufA, bufB);
  __syncthreads();
  mlp_layer<64, 64, true, 97, 97>(Wm1, 0.125f, bufB, bufA);
  __syncthreads();
  mlp_layer<64, 64, false, 97, 97>(Wm2, 0.125f, bufA, bufB);
  __syncthreads();
  for (int idx = t; idx < 64 * 64; idx += TB) {
    int ee = idx >> 6, j = idx & 63;
    float v = bufB[ee * 97 + j] * sEnv[ee];
    bufB[ee * 97 + j] = v;
    xg[(blk * EB + ee) * 64 + j] = v;
  }
  __syncthreads();
  // w1 scatter into nwY1
  {
    float acc[4] = {0.f, 0.f, 0.f, 0.f};
    for (int i = 0; i < 64; ++i) {
      float a = bufB[e * 97 + i];
      const float* wr = Ww1 + i * 32 + c0;
#pragma unroll
      for (int j = 0; j < 4; ++j) acc[j] = fmaf(a, wr[j], acc[j]);
    }
    int s = sSend[e];
#pragma unroll
    for (int j = 0; j < 4; ++j) {
      float w1 = acc[j] * 0.125f;
#pragma unroll
      for (int k = 0; k < 4; ++k)
        atomAddF(&nwY1[s * 128 + (c0 + j) * 4 + k], w1 * sY[e * 4 + k]);
    }
  }
}

// -------------------- K3: layer l=1 + readout --------------------
__global__ __launch_bounds__(TB) void k3_layer1(
    const float* __restrict__ vectors, const int* __restrict__ senders,
    const int* __restrict__ receivers,
    const float* __restrict__ Wm0, const float* __restrict__ Wm1,
    const float* __restrict__ Wm2, const float* __restrict__ Wr0,
    const float* __restrict__ Wrout,
    const float* __restrict__ xg, const float* __restrict__ h1g,
    const float* __restrict__ nwY1, float* __restrict__ out,
    const float* __restrict__ vepsp) {
  __shared__ float bufA[64 * 97];
  __shared__ float bufB[64 * 97];
  __shared__ float sNW[64 * 128];
  __shared__ float sH[64 * 32];
  __shared__ float sY[64 * 4];
  __shared__ float sEnv[64];
  __shared__ int sSend[64];
  __shared__ int sRecv[64];
  const int t = threadIdx.x;
  const int blk = blockIdx.x;
  const int e = t & 63;
  const float eps = rsqrtf(1.f + log1pf(__expf(vepsp[0])));
  const float INV_SQRT3 = 0.57735026918962576f;

  if (t < 64) {
    int eg = blk * EB + t;
    float vx = vectors[eg * 3 + 0], vy = vectors[eg * 3 + 1], vz = vectors[eg * 3 + 2];
    float d = fmaxf(sqrtf(vx * vx + vy * vy + vz * vz), 1e-6f);
    float d2 = d * d, d3 = d2 * d, d6 = d3 * d3;
    sEnv[t] = (d < 1.f) ? (1.f + d6 * (-28.f + 48.f * d - 21.f * d2)) : 0.f;
    float inv_d = 1.f / d;
    const float SQ3 = 1.7320508075688772f;
    sY[t * 4 + 0] = 1.f;
    sY[t * 4 + 1] = SQ3 * vx * inv_d;
    sY[t * 4 + 2] = SQ3 * vy * inv_d;
    sY[t * 4 + 3] = SQ3 * vz * inv_d;
    sSend[t] = senders[eg];
    sRecv[t] = receivers[eg];
  }
  __syncthreads();
  for (int idx = t; idx < 64 * 64; idx += TB) {
    int ee = idx >> 6, j = idx & 63;
    bufA[ee * 97 + j] = xg[(blk * EB + ee) * 64 + j];
  }
  for (int idx = t; idx < 64 * 128; idx += TB) {
    int ee = idx >> 7, j = idx & 127;
    sNW[ee * 128 + j] = nwY1[sSend[ee] * 128 + j];
  }
  for (int idx = t; idx < 64 * 32; idx += TB) {
    int ee = idx >> 5, j = idx & 31;
    sH[ee * 32 + j] = h1g[(blk * EB + ee) * 32 + j];
  }
  __syncthreads();
  const int c0 = __builtin_amdgcn_readfirstlane((t >> 6) * 4);
  {
#pragma unroll
    for (int j = 0; j < 4; ++j) {
      int c = c0 + j;
      float sk = sNW[e * 128 + c * 4 + 1] * sY[e * 4 + 1]
               + sNW[e * 128 + c * 4 + 2] * sY[e * 4 + 2]
               + sNW[e * 128 + c * 4 + 3] * sY[e * 4 + 3];
      bufA[e * 97 + 64 + c] = sH[e * 32 + c] * eps * sk * INV_SQRT3;
    }
  }
  __syncthreads();
  mlp_layer<96, 64, true, 97, 97>(Wm0, 0.10206207f, bufA, bufB);
  __syncthreads();
  mlp_layer<64, 64, true, 97, 97>(Wm1, 0.125f, bufB, bufA);
  __syncthreads();
  mlp_layer<64, 64, false, 97, 97>(Wm2, 0.125f, bufA, bufB);
  __syncthreads();
  for (int idx = t; idx < 64 * 64; idx += TB) {
    int ee = idx >> 6, j = idx & 63;
    bufB[ee * 97 + j] *= sEnv[ee];
  }
  __syncthreads();
  mlp_layer<64, 64, false, 97, 97>(Wr0, 0.125f, bufB, bufA);
  __syncthreads();
  if (t < 64) {
    float acc = 0.f;
    for (int i = 0; i < 64; ++i) acc = fmaf(bufA[t * 97 + i], Wrout[i], acc);
    acc *= 0.125f * sEnv[t];
    atomAddF(&out[sRecv[t]], acc);
  }
}

// -------------------- launch --------------------
extern "C" void kernel_launch(void* const* d_in, const int* in_sizes, int n_in,
                              void* d_out, int out_size, void* d_ws, size_t ws_size,
                              hipStream_t stream) {
  const float* vectors   = (const float*)d_in[0];
  const int*   senders   = (const int*)d_in[1];
  const int*   receivers = (const int*)d_in[2];
  const int*   species   = (const int*)d_in[3];
  const float* emb       = (const float*)d_in[4];
  const float* We0       = (const float*)d_in[5];
  const float* We1       = (const float*)d_in[6];
  const float* We2       = (const float*)d_in[7];
  const float* We3       = (const float*)d_in[8];
  const float* Wwvec     = (const float*)d_in[9];
  const float* Wvinit    = (const float*)d_in[10];
  const float* Ww        = (const float*)d_in[11];
  const float* Wm0       = (const float*)d_in[12];
  const float* Wm1       = (const float*)d_in[13];
  const float* Wm2       = (const float*)d_in[14];
  const float* WV        = (const float*)d_in[15];
  const float* Wr0       = (const float*)d_in[16];
  const float* Wrout     = (const float*)d_in[17];
  const float* pe        = (const float*)d_in[18];
  const float* veps      = (const float*)d_in[19];
  float* outp = (float*)d_out;

  float* ws = (float*)d_ws;
  float* xg   = ws;                    // E*64
  float* wvg  = xg + E_EDGES * 64;     // E
  float* h1g  = wvg + E_EDGES;         // E*32
  float* nwY0 = h1g + E_EDGES * 32;    // N*128
  float* nwY1 = nwY0 + N_NODES * 128;  // N*128

  const int nblk = E_EDGES / EB;  // 5000

  hipLaunchKernelGGL(k0_init, dim3(512), dim3(256), 0, stream,
                     nwY0, nwY1, outp, species, pe);
  hipLaunchKernelGGL(k1_edge, dim3(nblk), dim3(TB), 0, stream,
                     vectors, senders, receivers, species, emb,
                     We0, We1, We2, We3, Wwvec, Ww, xg, wvg, nwY0);
  hipLaunchKernelGGL(k2_layer0, dim3(nblk), dim3(TB), 0, stream,
                     vectors, senders, Wvinit, WV, Wm0, Wm1, Wm2,
                     Ww + 64 * 32, xg, wvg, h1g, nwY0, nwY1, veps);
  hipLaunchKernelGGL(k3_layer1, dim3(nblk), dim3(TB), 0, stream,
                     vectors, senders, receivers,
                     Wm0 + 96 * 64, Wm1 + 64 * 64, Wm2 + 64 * 64,
                     Wr0, Wrout, xg, h1g, nwY1, outp, veps);
}